// Round 2
// baseline (317.628 us; speedup 1.0000x reference)
//
#include <hip/hip_runtime.h>
#include <hip/hip_bf16.h>

typedef __attribute__((ext_vector_type(4))) float f32x4;
typedef __attribute__((ext_vector_type(8))) short bf16x8;

#define MFMA16(A, B, C) __builtin_amdgcn_mfma_f32_16x16x32_bf16(A, B, C, 0, 0, 0)

// 2*log2(e): tanh(x) = 1 - 2/(1 + 2^(C2*x))
#define C2 2.8853900817779268f
// C2 / sqrt(128), folded into Wq/bq so MFMA output is already exp2-scaled
#define QS (2.8853900817779268f / 11.313708498984761f)

__device__ __forceinline__ unsigned cvtpk_bf16(float lo, float hi) {
    unsigned r;
    asm("v_cvt_pk_bf16_f32 %0, %1, %2" : "=v"(r) : "v"(lo), "v"(hi));
    return r;
}

__device__ __forceinline__ bf16x8 pack8(float4 a, float4 b) {
    union { unsigned u[4]; bf16x8 v; } u;
    u.u[0] = cvtpk_bf16(a.x, a.y);
    u.u[1] = cvtpk_bf16(a.z, a.w);
    u.u[2] = cvtpk_bf16(b.x, b.y);
    u.u[3] = cvtpk_bf16(b.z, b.w);
    return u.v;
}

// ---------------------------------------------------------------------------
// Kernel 1: transpose + convert weights to bf16, fold scales, stash biases.
// ---------------------------------------------------------------------------
__global__ void prep_weights(const float* __restrict__ Wq, const float* __restrict__ bq,
                             const float* __restrict__ Wk, const float* __restrict__ bk,
                             const float* __restrict__ Wv, const float* __restrict__ bv,
                             __hip_bfloat16* __restrict__ Wqt, __hip_bfloat16* __restrict__ Wkt,
                             __hip_bfloat16* __restrict__ Wvt, float* __restrict__ bias) {
    int i = blockIdx.x * 256 + threadIdx.x;  // 64 blocks * 256 = 16384 exactly
    int k = i >> 7, o = i & 127;
    Wqt[o * 128 + k] = __float2bfloat16(Wq[i] * QS);
    Wkt[o * 128 + k] = __float2bfloat16(Wk[i]);
    Wvt[o * 128 + k] = __float2bfloat16(Wv[i] * 0.25f);  // head-mean folded into V
    if (i < 128) {
        bias[i]       = bq[i] * QS;
        bias[128 + i] = bk[i];
        bias[256 + i] = bv[i] * 0.25f;
    }
}

// ---------------------------------------------------------------------------
// Kernel 2: Q/K/V projections via 16x16x32 bf16 MFMA.
//   Qo, Ko: row-major [B*N][128] bf16 (Q pre-scaled by C2/sqrt(128))
//   Vt:     transposed [B][128][N] bf16 (pre-scaled by 0.25)
// ---------------------------------------------------------------------------
__global__ __launch_bounds__(256) void proj_qkv(
        const float* __restrict__ x, const float* __restrict__ cond,
        const __hip_bfloat16* __restrict__ Wqt, const __hip_bfloat16* __restrict__ Wkt,
        const __hip_bfloat16* __restrict__ Wvt, const float* __restrict__ bias,
        __hip_bfloat16* __restrict__ Qo, __hip_bfloat16* __restrict__ Ko,
        __hip_bfloat16* __restrict__ Vt) {
    const int lane = threadIdx.x & 63, wv = threadIdx.x >> 6;
    const int l15 = lane & 15, g = lane >> 4;
    const int row0 = blockIdx.x * 64 + wv * 16;   // 256 blocks x 64 rows

    f32x4 qa[8], ka[8], va[8];
#pragma unroll
    for (int ot = 0; ot < 8; ++ot) {
        float b0 = bias[16 * ot + l15];
        float b1 = bias[128 + 16 * ot + l15];
        float b2 = bias[256 + 16 * ot + l15];
        qa[ot] = (f32x4){b0, b0, b0, b0};
        ka[ot] = (f32x4){b1, b1, b1, b1};
        va[ot] = (f32x4){b2, b2, b2, b2};
    }

    const float* xp = x    + (size_t)(row0 + l15) * 128 + 8 * g;
    const float* cp = cond + (size_t)(row0 + l15) * 128 + 8 * g;
#pragma unroll
    for (int kk = 0; kk < 4; ++kk) {
        float4 x0 = *(const float4*)(xp + 32 * kk);
        float4 x1 = *(const float4*)(xp + 32 * kk + 4);
        float4 c0 = *(const float4*)(cp + 32 * kk);
        float4 c1 = *(const float4*)(cp + 32 * kk + 4);
        bf16x8 xa = pack8(x0, x1);
        bf16x8 ca = pack8(c0, c1);
#pragma unroll
        for (int ot = 0; ot < 8; ++ot) {
            const int wo = (16 * ot + l15) * 128 + 32 * kk + 8 * g;
            qa[ot] = MFMA16(xa, *(const bf16x8*)(Wqt + wo), qa[ot]);
            ka[ot] = MFMA16(ca, *(const bf16x8*)(Wkt + wo), ka[ot]);
            va[ot] = MFMA16(ca, *(const bf16x8*)(Wvt + wo), va[ot]);
        }
    }

    // Q, K row-major stores (C/D layout: row = 4g+r, col = 16ot+l15)
#pragma unroll
    for (int ot = 0; ot < 8; ++ot)
#pragma unroll
        for (int r = 0; r < 4; ++r) {
            size_t idx = (size_t)(row0 + 4 * g + r) * 128 + 16 * ot + l15;
            Qo[idx] = __float2bfloat16(qa[ot][r]);
            Ko[idx] = __float2bfloat16(ka[ot][r]);
        }
    // V transposed store: lane holds 4 consecutive n for fixed d -> dwordx2
    const int bb = row0 >> 11, nn = (row0 & 2047) + 4 * g;
#pragma unroll
    for (int ot = 0; ot < 8; ++ot) {
        uint2 pr;
        pr.x = cvtpk_bf16(va[ot][0], va[ot][1]);
        pr.y = cvtpk_bf16(va[ot][2], va[ot][3]);
        *(uint2*)((unsigned short*)Vt + ((size_t)bb * 128 + 16 * ot + l15) * 2048 + nn) = pr;
    }
}

// ---------------------------------------------------------------------------
// Kernel 3: fused tanh-attention main loop.
// Block: 256 threads / 4 waves; block owns 16 Q-rows; wave w owns m-quarter.
// Swapped QK MFMA (K as A-operand) puts C/D as (row=m_local, col=q): mask
// loads become coalesced float4, LDS transpose-writes become packed-bf16 b64.
// NO barriers in the m-loop: transpose buffer is wave-private (in-wave DS ops
// are ordered by HW), so global loads stay in flight across chunks.
// ---------------------------------------------------------------------------
__global__ __launch_bounds__(256, 8) void attn_main(
        const __hip_bfloat16* __restrict__ Q, const __hip_bfloat16* __restrict__ K,
        const __hip_bfloat16* __restrict__ Vt, const float* __restrict__ mask,
        float* __restrict__ out) {
    // union: per-wave bf16 transpose tiles [16][72] (9216 B) / epilogue Red
    // regions 2 x [16][132] f32 (16896 B)
    __shared__ __align__(16) char LDSB[16896];

    const int lane = threadIdx.x & 63, w = threadIdx.x >> 6;
    const int l15 = lane & 15, g = lane >> 4;
    const int b = blockIdx.x >> 7;
    const int n0 = (blockIdx.x & 127) * 16;

    unsigned* Swu = (unsigned*)LDSB + w * (16 * 36);  // wave-private, stride 36 u32 = 72 bf16
    float* Red = (float*)LDSB;

    const __hip_bfloat16* Qb = Q + ((size_t)b * 2048 + n0) * 128;
    const __hip_bfloat16* Kb = K + (size_t)b * 2048 * 128;
    const unsigned short* Vb = (const unsigned short*)Vt + (size_t)b * 128 * 2048;
    const float* mrowq = mask + ((size_t)b * 2048 + n0 + l15) * 2048;  // per-lane q-row

    bf16x8 qf[4];
#pragma unroll
    for (int h = 0; h < 4; ++h)
        qf[h] = *(const bf16x8*)(Qb + l15 * 128 + 32 * h + 8 * g);

    f32x4 oacc[8];
#pragma unroll
    for (int dt = 0; dt < 8; ++dt) oacc[dt] = (f32x4){0.f, 0.f, 0.f, 0.f};
    const f32x4 zero = (f32x4){0.f, 0.f, 0.f, 0.f};

    for (int m0 = w * 512; m0 < w * 512 + 512; m0 += 64) {
#pragma unroll
        for (int st = 0; st < 4; ++st) {
            const int m = m0 + st * 16;
            const __hip_bfloat16* kp = Kb + (size_t)(m + l15) * 128 + 8 * g;
            // swapped operands: D[row=4g+r -> m_local][col=l15 -> q]
            f32x4 s0 = MFMA16(*(const bf16x8*)(kp),      qf[0], zero);
            f32x4 s1 = MFMA16(*(const bf16x8*)(kp + 32), qf[1], zero);
            f32x4 s2 = MFMA16(*(const bf16x8*)(kp + 64), qf[2], zero);
            f32x4 s3 = MFMA16(*(const bf16x8*)(kp + 96), qf[3], zero);
            // coalesced mask: lane reads 4 consecutive m at its q-row
            f32x4 mk = *(const f32x4*)(mrowq + m + 4 * g);
            float acd[4];
#pragma unroll
            for (int r = 0; r < 4; ++r) {
                float m2 = mk[r] * C2;
                float e0 = __builtin_amdgcn_exp2f(m2 + s0[r]);
                float e1 = __builtin_amdgcn_exp2f(m2 + s1[r]);
                float e2 = __builtin_amdgcn_exp2f(m2 + s2[r]);
                float e3 = __builtin_amdgcn_exp2f(m2 + s3[r]);
                float rs = __builtin_amdgcn_rcpf(1.f + e0) + __builtin_amdgcn_rcpf(1.f + e1)
                         + __builtin_amdgcn_rcpf(1.f + e2) + __builtin_amdgcn_rcpf(1.f + e3);
                acd[r] = 4.f - 2.f * rs;   // sum_h tanh(...)
            }
            // packed-bf16 transpose write: row q=l15, cols m_local=16st+4g+0..3
            uint2 pk;
            pk.x = cvtpk_bf16(acd[0], acd[1]);
            pk.y = cvtpk_bf16(acd[2], acd[3]);
            *(uint2*)(Swu + l15 * 36 + st * 8 + 2 * g) = pk;
        }
        // PV: A-frag = row l15, m-slice ks*32+8g..+7 (contiguous bf16 -> b128)
#pragma unroll
        for (int ks = 0; ks < 2; ++ks) {
            bf16x8 af = *(const bf16x8*)(Swu + l15 * 36 + ks * 16 + 4 * g);
#pragma unroll
            for (int dt = 0; dt < 8; ++dt) {
                const bf16x8 vf = *(const bf16x8*)(
                    Vb + (size_t)(16 * dt + l15) * 2048 + m0 + 32 * ks + 8 * g);
                oacc[dt] = MFMA16(af, vf, oacc[dt]);
            }
        }
    }

    // epilogue: reduce 4 m-quarter partials (Red aliases transpose tiles)
    __syncthreads();
    if (w >= 2)
#pragma unroll
        for (int dt = 0; dt < 8; ++dt)
#pragma unroll
            for (int r = 0; r < 4; ++r)
                Red[(w - 2) * 2112 + (4 * g + r) * 132 + 16 * dt + l15] = oacc[dt][r];
    __syncthreads();
    if (w < 2)
#pragma unroll
        for (int dt = 0; dt < 8; ++dt)
#pragma unroll
            for (int r = 0; r < 4; ++r)
                oacc[dt][r] += Red[w * 2112 + (4 * g + r) * 132 + 16 * dt + l15];
    __syncthreads();
    if (w == 1)
#pragma unroll
        for (int dt = 0; dt < 8; ++dt)
#pragma unroll
            for (int r = 0; r < 4; ++r)
                Red[(4 * g + r) * 132 + 16 * dt + l15] = oacc[dt][r];
    __syncthreads();
    if (w == 0) {
        float* ob = out + ((size_t)b * 2048 + n0) * 128;
#pragma unroll
        for (int dt = 0; dt < 8; ++dt)
#pragma unroll
            for (int r = 0; r < 4; ++r)
                ob[(size_t)(4 * g + r) * 128 + 16 * dt + l15] =
                    oacc[dt][r] + Red[(4 * g + r) * 132 + 16 * dt + l15];
    }
}

// ---------------------------------------------------------------------------
extern "C" void kernel_launch(void* const* d_in, const int* in_sizes, int n_in,
                              void* d_out, int out_size, void* d_ws, size_t ws_size,
                              hipStream_t stream) {
    const float* x    = (const float*)d_in[0];
    const float* cond = (const float*)d_in[1];
    // d_in[2] = flags (unused by reference)
    const float* mask = (const float*)d_in[3];
    const float* Wq = (const float*)d_in[4];
    const float* bq = (const float*)d_in[5];
    const float* Wk = (const float*)d_in[6];
    const float* bk = (const float*)d_in[7];
    const float* Wv = (const float*)d_in[8];
    const float* bv = (const float*)d_in[9];
    float* out = (float*)d_out;

    char* ws = (char*)d_ws;
    __hip_bfloat16* Qo  = (__hip_bfloat16*)(ws);                       // 4 MB
    __hip_bfloat16* Ko  = (__hip_bfloat16*)(ws + (4  << 20));          // 4 MB
    __hip_bfloat16* Vt  = (__hip_bfloat16*)(ws + (8  << 20));          // 4 MB
    __hip_bfloat16* Wqt = (__hip_bfloat16*)(ws + (12 << 20));          // 32 KB
    __hip_bfloat16* Wkt = (__hip_bfloat16*)(ws + (12 << 20) + 32768);
    __hip_bfloat16* Wvt = (__hip_bfloat16*)(ws + (12 << 20) + 65536);
    float*          bias = (float*)(ws + (12 << 20) + 98304);          // 1.5 KB

    prep_weights<<<64, 256, 0, stream>>>(Wq, bq, Wk, bk, Wv, bv, Wqt, Wkt, Wvt, bias);
    proj_qkv<<<256, 256, 0, stream>>>(x, cond, Wqt, Wkt, Wvt, bias, Qo, Ko, Vt);
    attn_main<<<1024, 256, 0, stream>>>(Qo, Ko, Vt, mask, out);
}

// Round 3
// 159.558 us; speedup vs baseline: 1.9907x; 1.9907x over previous
//
#include <hip/hip_runtime.h>
#include <hip/hip_bf16.h>

typedef __attribute__((ext_vector_type(4))) float f32x4;
typedef __attribute__((ext_vector_type(8))) short bf16x8;

#define MFMA16(A, B, C) __builtin_amdgcn_mfma_f32_16x16x32_bf16(A, B, C, 0, 0, 0)

// 2*log2(e): tanh(x) = 1 - 2/(1 + 2^(C2*x))
#define C2 2.8853900817779268f
// C2 / sqrt(128), folded into Wq/bq so MFMA output is already exp2-scaled
#define QS (2.8853900817779268f / 11.313708498984761f)

__device__ __forceinline__ unsigned cvtpk_bf16(float lo, float hi) {
    unsigned r;
    asm("v_cvt_pk_bf16_f32 %0, %1, %2" : "=v"(r) : "v"(lo), "v"(hi));
    return r;
}

__device__ __forceinline__ bf16x8 pack8(float4 a, float4 b) {
    union { unsigned u[4]; bf16x8 v; } u;
    u.u[0] = cvtpk_bf16(a.x, a.y);
    u.u[1] = cvtpk_bf16(a.z, a.w);
    u.u[2] = cvtpk_bf16(b.x, b.y);
    u.u[3] = cvtpk_bf16(b.z, b.w);
    return u.v;
}

// ---------------------------------------------------------------------------
// Kernel 1: transpose + convert weights to bf16, fold scales, stash biases.
// ---------------------------------------------------------------------------
__global__ void prep_weights(const float* __restrict__ Wq, const float* __restrict__ bq,
                             const float* __restrict__ Wk, const float* __restrict__ bk,
                             const float* __restrict__ Wv, const float* __restrict__ bv,
                             __hip_bfloat16* __restrict__ Wqt, __hip_bfloat16* __restrict__ Wkt,
                             __hip_bfloat16* __restrict__ Wvt, float* __restrict__ bias) {
    int i = blockIdx.x * 256 + threadIdx.x;  // 64 blocks * 256 = 16384 exactly
    int k = i >> 7, o = i & 127;
    Wqt[o * 128 + k] = __float2bfloat16(Wq[i] * QS);
    Wkt[o * 128 + k] = __float2bfloat16(Wk[i]);
    Wvt[o * 128 + k] = __float2bfloat16(Wv[i] * 0.25f);  // head-mean folded into V
    if (i < 128) {
        bias[i]       = bq[i] * QS;
        bias[128 + i] = bk[i];
        bias[256 + i] = bv[i] * 0.25f;
    }
}

// ---------------------------------------------------------------------------
// Kernel 2: Q/K/V projections via 16x16x32 bf16 MFMA.
//   Qo, Ko: row-major [B*N][128] bf16 (Q pre-scaled by C2/sqrt(128))
//   Vt:     transposed [B][128][N] bf16 (pre-scaled by 0.25)
// ---------------------------------------------------------------------------
__global__ __launch_bounds__(256) void proj_qkv(
        const float* __restrict__ x, const float* __restrict__ cond,
        const __hip_bfloat16* __restrict__ Wqt, const __hip_bfloat16* __restrict__ Wkt,
        const __hip_bfloat16* __restrict__ Wvt, const float* __restrict__ bias,
        __hip_bfloat16* __restrict__ Qo, __hip_bfloat16* __restrict__ Ko,
        __hip_bfloat16* __restrict__ Vt) {
    const int lane = threadIdx.x & 63, wv = threadIdx.x >> 6;
    const int l15 = lane & 15, g = lane >> 4;
    const int row0 = blockIdx.x * 64 + wv * 16;   // 256 blocks x 64 rows

    f32x4 qa[8], ka[8], va[8];
#pragma unroll
    for (int ot = 0; ot < 8; ++ot) {
        float b0 = bias[16 * ot + l15];
        float b1 = bias[128 + 16 * ot + l15];
        float b2 = bias[256 + 16 * ot + l15];
        qa[ot] = (f32x4){b0, b0, b0, b0};
        ka[ot] = (f32x4){b1, b1, b1, b1};
        va[ot] = (f32x4){b2, b2, b2, b2};
    }

    const float* xp = x    + (size_t)(row0 + l15) * 128 + 8 * g;
    const float* cp = cond + (size_t)(row0 + l15) * 128 + 8 * g;
#pragma unroll
    for (int kk = 0; kk < 4; ++kk) {
        float4 x0 = *(const float4*)(xp + 32 * kk);
        float4 x1 = *(const float4*)(xp + 32 * kk + 4);
        float4 c0 = *(const float4*)(cp + 32 * kk);
        float4 c1 = *(const float4*)(cp + 32 * kk + 4);
        bf16x8 xa = pack8(x0, x1);
        bf16x8 ca = pack8(c0, c1);
#pragma unroll
        for (int ot = 0; ot < 8; ++ot) {
            const int wo = (16 * ot + l15) * 128 + 32 * kk + 8 * g;
            qa[ot] = MFMA16(xa, *(const bf16x8*)(Wqt + wo), qa[ot]);
            ka[ot] = MFMA16(ca, *(const bf16x8*)(Wkt + wo), ka[ot]);
            va[ot] = MFMA16(ca, *(const bf16x8*)(Wvt + wo), va[ot]);
        }
    }

    // Q, K row-major stores (C/D layout: row = 4g+r, col = 16ot+l15)
#pragma unroll
    for (int ot = 0; ot < 8; ++ot)
#pragma unroll
        for (int r = 0; r < 4; ++r) {
            size_t idx = (size_t)(row0 + 4 * g + r) * 128 + 16 * ot + l15;
            Qo[idx] = __float2bfloat16(qa[ot][r]);
            Ko[idx] = __float2bfloat16(ka[ot][r]);
        }
    // V transposed store: lane holds 4 consecutive n for fixed d -> dwordx2
    const int bb = row0 >> 11, nn = (row0 & 2047) + 4 * g;
#pragma unroll
    for (int ot = 0; ot < 8; ++ot) {
        uint2 pr;
        pr.x = cvtpk_bf16(va[ot][0], va[ot][1]);
        pr.y = cvtpk_bf16(va[ot][2], va[ot][3]);
        *(uint2*)((unsigned short*)Vt + ((size_t)bb * 128 + 16 * ot + l15) * 2048 + nn) = pr;
    }
}

// ---------------------------------------------------------------------------
// Kernel 3: fused tanh-attention main loop.
// Block: 256 threads / 4 waves; block owns 16 Q-rows; wave w owns m-quarter.
// Swapped QK MFMA (K as A-operand) puts C/D as (row=m_local, col=q): mask
// loads become coalesced float4, LDS transpose-writes become packed-bf16 b64.
// NO barriers in the m-loop: transpose buffer is wave-private (in-wave DS ops
// are ordered by HW), so global loads stay in flight across chunks.
// NOTE: no min-waves launch bound — (256,8) forced VGPR<=64 and spilled
// 342 MB of scratch per dispatch (round-2 post-mortem).
// ---------------------------------------------------------------------------
__global__ __launch_bounds__(256) void attn_main(
        const __hip_bfloat16* __restrict__ Q, const __hip_bfloat16* __restrict__ K,
        const __hip_bfloat16* __restrict__ Vt, const float* __restrict__ mask,
        float* __restrict__ out) {
    // union: per-wave bf16 transpose tiles [16][72] (9216 B) / epilogue Red
    // regions 2 x [16][132] f32 (16896 B)
    __shared__ __align__(16) char LDSB[16896];

    const int lane = threadIdx.x & 63, w = threadIdx.x >> 6;
    const int l15 = lane & 15, g = lane >> 4;
    const int b = blockIdx.x >> 7;
    const int n0 = (blockIdx.x & 127) * 16;

    unsigned* Swu = (unsigned*)LDSB + w * (16 * 36);  // wave-private, stride 36 u32 = 72 bf16
    float* Red = (float*)LDSB;

    const __hip_bfloat16* Qb = Q + ((size_t)b * 2048 + n0) * 128;
    const __hip_bfloat16* Kb = K + (size_t)b * 2048 * 128;
    const unsigned short* Vb = (const unsigned short*)Vt + (size_t)b * 128 * 2048;
    const float* mrowq = mask + ((size_t)b * 2048 + n0 + l15) * 2048;  // per-lane q-row

    bf16x8 qf[4];
#pragma unroll
    for (int h = 0; h < 4; ++h)
        qf[h] = *(const bf16x8*)(Qb + l15 * 128 + 32 * h + 8 * g);

    f32x4 oacc[8];
#pragma unroll
    for (int dt = 0; dt < 8; ++dt) oacc[dt] = (f32x4){0.f, 0.f, 0.f, 0.f};
    const f32x4 zero = (f32x4){0.f, 0.f, 0.f, 0.f};

    for (int m0 = w * 512; m0 < w * 512 + 512; m0 += 64) {
#pragma unroll
        for (int st = 0; st < 4; ++st) {
            const int m = m0 + st * 16;
            const __hip_bfloat16* kp = Kb + (size_t)(m + l15) * 128 + 8 * g;
            // swapped operands: D[row=4g+r -> m_local][col=l15 -> q]
            f32x4 s0 = MFMA16(*(const bf16x8*)(kp),      qf[0], zero);
            f32x4 s1 = MFMA16(*(const bf16x8*)(kp + 32), qf[1], zero);
            f32x4 s2 = MFMA16(*(const bf16x8*)(kp + 64), qf[2], zero);
            f32x4 s3 = MFMA16(*(const bf16x8*)(kp + 96), qf[3], zero);
            // coalesced mask: lane reads 4 consecutive m at its q-row
            f32x4 mk = *(const f32x4*)(mrowq + m + 4 * g);
            float acd[4];
#pragma unroll
            for (int r = 0; r < 4; ++r) {
                float m2 = mk[r] * C2;
                float e0 = __builtin_amdgcn_exp2f(m2 + s0[r]);
                float e1 = __builtin_amdgcn_exp2f(m2 + s1[r]);
                float e2 = __builtin_amdgcn_exp2f(m2 + s2[r]);
                float e3 = __builtin_amdgcn_exp2f(m2 + s3[r]);
                float rs = __builtin_amdgcn_rcpf(1.f + e0) + __builtin_amdgcn_rcpf(1.f + e1)
                         + __builtin_amdgcn_rcpf(1.f + e2) + __builtin_amdgcn_rcpf(1.f + e3);
                acd[r] = 4.f - 2.f * rs;   // sum_h tanh(...)
            }
            // packed-bf16 transpose write: row q=l15, cols m_local=16st+4g+0..3
            uint2 pk;
            pk.x = cvtpk_bf16(acd[0], acd[1]);
            pk.y = cvtpk_bf16(acd[2], acd[3]);
            *(uint2*)(Swu + l15 * 36 + st * 8 + 2 * g) = pk;
        }
        // PV: A-frag = row l15, m-slice ks*32+8g..+7 (contiguous bf16 -> b128)
#pragma unroll
        for (int ks = 0; ks < 2; ++ks) {
            bf16x8 af = *(const bf16x8*)(Swu + l15 * 36 + ks * 16 + 4 * g);
#pragma unroll
            for (int dt = 0; dt < 8; ++dt) {
                const bf16x8 vf = *(const bf16x8*)(
                    Vb + (size_t)(16 * dt + l15) * 2048 + m0 + 32 * ks + 8 * g);
                oacc[dt] = MFMA16(af, vf, oacc[dt]);
            }
        }
    }

    // epilogue: reduce 4 m-quarter partials (Red aliases transpose tiles)
    __syncthreads();
    if (w >= 2)
#pragma unroll
        for (int dt = 0; dt < 8; ++dt)
#pragma unroll
            for (int r = 0; r < 4; ++r)
                Red[(w - 2) * 2112 + (4 * g + r) * 132 + 16 * dt + l15] = oacc[dt][r];
    __syncthreads();
    if (w < 2)
#pragma unroll
        for (int dt = 0; dt < 8; ++dt)
#pragma unroll
            for (int r = 0; r < 4; ++r)
                oacc[dt][r] += Red[w * 2112 + (4 * g + r) * 132 + 16 * dt + l15];
    __syncthreads();
    if (w == 1)
#pragma unroll
        for (int dt = 0; dt < 8; ++dt)
#pragma unroll
            for (int r = 0; r < 4; ++r)
                Red[(4 * g + r) * 132 + 16 * dt + l15] = oacc[dt][r];
    __syncthreads();
    if (w == 0) {
        float* ob = out + ((size_t)b * 2048 + n0) * 128;
#pragma unroll
        for (int dt = 0; dt < 8; ++dt)
#pragma unroll
            for (int r = 0; r < 4; ++r)
                ob[(size_t)(4 * g + r) * 128 + 16 * dt + l15] =
                    oacc[dt][r] + Red[(4 * g + r) * 132 + 16 * dt + l15];
    }
}

// ---------------------------------------------------------------------------
extern "C" void kernel_launch(void* const* d_in, const int* in_sizes, int n_in,
                              void* d_out, int out_size, void* d_ws, size_t ws_size,
                              hipStream_t stream) {
    const float* x    = (const float*)d_in[0];
    const float* cond = (const float*)d_in[1];
    // d_in[2] = flags (unused by reference)
    const float* mask = (const float*)d_in[3];
    const float* Wq = (const float*)d_in[4];
    const float* bq = (const float*)d_in[5];
    const float* Wk = (const float*)d_in[6];
    const float* bk = (const float*)d_in[7];
    const float* Wv = (const float*)d_in[8];
    const float* bv = (const float*)d_in[9];
    float* out = (float*)d_out;

    char* ws = (char*)d_ws;
    __hip_bfloat16* Qo  = (__hip_bfloat16*)(ws);                       // 4 MB
    __hip_bfloat16* Ko  = (__hip_bfloat16*)(ws + (4  << 20));          // 4 MB
    __hip_bfloat16* Vt  = (__hip_bfloat16*)(ws + (8  << 20));          // 4 MB
    __hip_bfloat16* Wqt = (__hip_bfloat16*)(ws + (12 << 20));          // 32 KB
    __hip_bfloat16* Wkt = (__hip_bfloat16*)(ws + (12 << 20) + 32768);
    __hip_bfloat16* Wvt = (__hip_bfloat16*)(ws + (12 << 20) + 65536);
    float*          bias = (float*)(ws + (12 << 20) + 98304);          // 1.5 KB

    prep_weights<<<64, 256, 0, stream>>>(Wq, bq, Wk, bk, Wv, bv, Wqt, Wkt, Wvt, bias);
    proj_qkv<<<256, 256, 0, stream>>>(x, cond, Wqt, Wkt, Wvt, bias, Qo, Ko, Vt);
    attn_main<<<1024, 256, 0, stream>>>(Qo, Ko, Vt, mask, out);
}

// Round 4
// 158.780 us; speedup vs baseline: 2.0004x; 1.0049x over previous
//
#include <hip/hip_runtime.h>
#include <hip/hip_bf16.h>

typedef __attribute__((ext_vector_type(4))) float f32x4;
typedef __attribute__((ext_vector_type(8))) short bf16x8;

#define MFMA16(A, B, C) __builtin_amdgcn_mfma_f32_16x16x32_bf16(A, B, C, 0, 0, 0)

// 2*log2(e): tanh(x) = 1 - 2/(1 + 2^(C2*x))
#define C2 2.8853900817779268f
// C2 / sqrt(128), folded into Wq/bq so MFMA output is already exp2-scaled
#define QS (2.8853900817779268f / 11.313708498984761f)

__device__ __forceinline__ unsigned cvtpk_bf16(float lo, float hi) {
    unsigned r;
    asm("v_cvt_pk_bf16_f32 %0, %1, %2" : "=v"(r) : "v"(lo), "v"(hi));
    return r;
}

__device__ __forceinline__ bf16x8 pack8(float4 a, float4 b) {
    union { unsigned u[4]; bf16x8 v; } u;
    u.u[0] = cvtpk_bf16(a.x, a.y);
    u.u[1] = cvtpk_bf16(a.z, a.w);
    u.u[2] = cvtpk_bf16(b.x, b.y);
    u.u[3] = cvtpk_bf16(b.z, b.w);
    return u.v;
}

// ---------------------------------------------------------------------------
// Kernel 1: transpose + convert weights to bf16, fold scales, stash biases.
// ---------------------------------------------------------------------------
__global__ void prep_weights(const float* __restrict__ Wq, const float* __restrict__ bq,
                             const float* __restrict__ Wk, const float* __restrict__ bk,
                             const float* __restrict__ Wv, const float* __restrict__ bv,
                             __hip_bfloat16* __restrict__ Wqt, __hip_bfloat16* __restrict__ Wkt,
                             __hip_bfloat16* __restrict__ Wvt, float* __restrict__ bias) {
    int i = blockIdx.x * 256 + threadIdx.x;  // 64 blocks * 256 = 16384 exactly
    int k = i >> 7, o = i & 127;
    Wqt[o * 128 + k] = __float2bfloat16(Wq[i] * QS);
    Wkt[o * 128 + k] = __float2bfloat16(Wk[i]);
    Wvt[o * 128 + k] = __float2bfloat16(Wv[i] * 0.25f);  // head-mean folded into V
    if (i < 128) {
        bias[i]       = bq[i] * QS;
        bias[128 + i] = bk[i];
        bias[256 + i] = bv[i] * 0.25f;
    }
}

// ---------------------------------------------------------------------------
// Kernel 2: Q/K/V projections via 16x16x32 bf16 MFMA.
//   Qo, Ko: row-major [B*N][128] bf16 (Q pre-scaled by C2/sqrt(128))
//   Vt:     transposed [B][128][N] bf16 (pre-scaled by 0.25)
// ---------------------------------------------------------------------------
__global__ __launch_bounds__(256) void proj_qkv(
        const float* __restrict__ x, const float* __restrict__ cond,
        const __hip_bfloat16* __restrict__ Wqt, const __hip_bfloat16* __restrict__ Wkt,
        const __hip_bfloat16* __restrict__ Wvt, const float* __restrict__ bias,
        __hip_bfloat16* __restrict__ Qo, __hip_bfloat16* __restrict__ Ko,
        __hip_bfloat16* __restrict__ Vt) {
    const int lane = threadIdx.x & 63, wv = threadIdx.x >> 6;
    const int l15 = lane & 15, g = lane >> 4;
    const int row0 = blockIdx.x * 64 + wv * 16;   // 256 blocks x 64 rows

    f32x4 qa[8], ka[8], va[8];
#pragma unroll
    for (int ot = 0; ot < 8; ++ot) {
        float b0 = bias[16 * ot + l15];
        float b1 = bias[128 + 16 * ot + l15];
        float b2 = bias[256 + 16 * ot + l15];
        qa[ot] = (f32x4){b0, b0, b0, b0};
        ka[ot] = (f32x4){b1, b1, b1, b1};
        va[ot] = (f32x4){b2, b2, b2, b2};
    }

    const float* xp = x    + (size_t)(row0 + l15) * 128 + 8 * g;
    const float* cp = cond + (size_t)(row0 + l15) * 128 + 8 * g;
#pragma unroll
    for (int kk = 0; kk < 4; ++kk) {
        float4 x0 = *(const float4*)(xp + 32 * kk);
        float4 x1 = *(const float4*)(xp + 32 * kk + 4);
        float4 c0 = *(const float4*)(cp + 32 * kk);
        float4 c1 = *(const float4*)(cp + 32 * kk + 4);
        bf16x8 xa = pack8(x0, x1);
        bf16x8 ca = pack8(c0, c1);
#pragma unroll
        for (int ot = 0; ot < 8; ++ot) {
            const int wo = (16 * ot + l15) * 128 + 32 * kk + 8 * g;
            qa[ot] = MFMA16(xa, *(const bf16x8*)(Wqt + wo), qa[ot]);
            ka[ot] = MFMA16(ca, *(const bf16x8*)(Wkt + wo), ka[ot]);
            va[ot] = MFMA16(ca, *(const bf16x8*)(Wvt + wo), va[ot]);
        }
    }

    // Q, K row-major stores (C/D layout: row = 4g+r, col = 16ot+l15)
#pragma unroll
    for (int ot = 0; ot < 8; ++ot)
#pragma unroll
        for (int r = 0; r < 4; ++r) {
            size_t idx = (size_t)(row0 + 4 * g + r) * 128 + 16 * ot + l15;
            Qo[idx] = __float2bfloat16(qa[ot][r]);
            Ko[idx] = __float2bfloat16(ka[ot][r]);
        }
    // V transposed store: lane holds 4 consecutive n for fixed d -> dwordx2
    const int bb = row0 >> 11, nn = (row0 & 2047) + 4 * g;
#pragma unroll
    for (int ot = 0; ot < 8; ++ot) {
        uint2 pr;
        pr.x = cvtpk_bf16(va[ot][0], va[ot][1]);
        pr.y = cvtpk_bf16(va[ot][2], va[ot][3]);
        *(uint2*)((unsigned short*)Vt + ((size_t)bb * 128 + 16 * ot + l15) * 2048 + nn) = pr;
    }
}

// ---------------------------------------------------------------------------
// Kernel 3: fused tanh-attention main loop.
// Block: 256 threads / 4 waves; block owns 16 Q-rows; wave w owns m-quarter.
// Swapped QK MFMA (K as A-operand): C/D = (row=m_local, col=q) -> coalesced
// float4 mask loads, packed-bf16 LDS transpose. No barriers in the m-loop
// (transpose tile is wave-private; in-wave DS ops are HW-ordered).
// R4: chunk loop fully unrolled + explicit 2-buffer register prefetch of the
// NEXT chunk's mask (the only HBM-latency stream) issued before ~1300 cycles
// of current-chunk compute. Static buffer indices (no scratch).
// ---------------------------------------------------------------------------
__global__ __launch_bounds__(256) void attn_main(
        const __hip_bfloat16* __restrict__ Q, const __hip_bfloat16* __restrict__ K,
        const __hip_bfloat16* __restrict__ Vt, const float* __restrict__ mask,
        float* __restrict__ out) {
    // union: per-wave bf16 transpose tiles [16][72] (9216 B) / epilogue Red
    // regions 2 x [16][132] f32 (16896 B)
    __shared__ __align__(16) char LDSB[16896];

    const int lane = threadIdx.x & 63, w = threadIdx.x >> 6;
    const int l15 = lane & 15, g = lane >> 4;
    const int b = blockIdx.x >> 7;
    const int n0 = (blockIdx.x & 127) * 16;

    unsigned* Swu = (unsigned*)LDSB + w * (16 * 36);  // wave-private, stride 36 u32
    float* Red = (float*)LDSB;

    const __hip_bfloat16* Qb = Q + ((size_t)b * 2048 + n0) * 128;
    const __hip_bfloat16* Kb = K + (size_t)b * 2048 * 128;
    const unsigned short* Vb = (const unsigned short*)Vt + (size_t)b * 128 * 2048;
    // per-lane q-row, m-column base 4g; wave's m-quarter starts at w*512
    const float* mrowq = mask + ((size_t)b * 2048 + n0 + l15) * 2048 + w * 512 + 4 * g;

    bf16x8 qf[4];
#pragma unroll
    for (int h = 0; h < 4; ++h)
        qf[h] = *(const bf16x8*)(Qb + l15 * 128 + 32 * h + 8 * g);

    f32x4 oacc[8];
#pragma unroll
    for (int dt = 0; dt < 8; ++dt) oacc[dt] = (f32x4){0.f, 0.f, 0.f, 0.f};
    const f32x4 zero = (f32x4){0.f, 0.f, 0.f, 0.f};

    // 2-buffer register prefetch of the mask stream (chunk-deep)
    f32x4 mk[2][4];
#pragma unroll
    for (int st = 0; st < 4; ++st)
        mk[0][st] = *(const f32x4*)(mrowq + st * 16);

#pragma unroll
    for (int c = 0; c < 8; ++c) {
        const int m0 = w * 512 + c * 64;
        // issue next chunk's mask loads NOW; ~1300 cycles of compute below
        if (c < 7) {
#pragma unroll
            for (int st = 0; st < 4; ++st)
                mk[(c + 1) & 1][st] = *(const f32x4*)(mrowq + (c + 1) * 64 + st * 16);
        }
#pragma unroll
        for (int st = 0; st < 4; ++st) {
            const int m = m0 + st * 16;
            const __hip_bfloat16* kp = Kb + (size_t)(m + l15) * 128 + 8 * g;
            // swapped operands: D[row=4g+r -> m_local][col=l15 -> q]
            f32x4 s0 = MFMA16(*(const bf16x8*)(kp),      qf[0], zero);
            f32x4 s1 = MFMA16(*(const bf16x8*)(kp + 32), qf[1], zero);
            f32x4 s2 = MFMA16(*(const bf16x8*)(kp + 64), qf[2], zero);
            f32x4 s3 = MFMA16(*(const bf16x8*)(kp + 96), qf[3], zero);
            const f32x4 mkc = mk[c & 1][st];
            float acd[4];
#pragma unroll
            for (int r = 0; r < 4; ++r) {
                float m2 = mkc[r] * C2;
                float e0 = __builtin_amdgcn_exp2f(m2 + s0[r]);
                float e1 = __builtin_amdgcn_exp2f(m2 + s1[r]);
                float e2 = __builtin_amdgcn_exp2f(m2 + s2[r]);
                float e3 = __builtin_amdgcn_exp2f(m2 + s3[r]);
                float rs = __builtin_amdgcn_rcpf(1.f + e0) + __builtin_amdgcn_rcpf(1.f + e1)
                         + __builtin_amdgcn_rcpf(1.f + e2) + __builtin_amdgcn_rcpf(1.f + e3);
                acd[r] = 4.f - 2.f * rs;   // sum_h tanh(...)
            }
            // packed-bf16 transpose write: row q=l15, cols m_local=16st+4g+0..3
            uint2 pk;
            pk.x = cvtpk_bf16(acd[0], acd[1]);
            pk.y = cvtpk_bf16(acd[2], acd[3]);
            *(uint2*)(Swu + l15 * 36 + st * 8 + 2 * g) = pk;
        }
        // PV: A-frag = row l15, m-slice ks*32+8g..+7 (contiguous bf16 -> b128)
#pragma unroll
        for (int ks = 0; ks < 2; ++ks) {
            bf16x8 af = *(const bf16x8*)(Swu + l15 * 36 + ks * 16 + 4 * g);
#pragma unroll
            for (int dt = 0; dt < 8; ++dt) {
                const bf16x8 vf = *(const bf16x8*)(
                    Vb + (size_t)(16 * dt + l15) * 2048 + m0 + 32 * ks + 8 * g);
                oacc[dt] = MFMA16(af, vf, oacc[dt]);
            }
        }
    }

    // epilogue: reduce 4 m-quarter partials (Red aliases transpose tiles)
    __syncthreads();
    if (w >= 2)
#pragma unroll
        for (int dt = 0; dt < 8; ++dt)
#pragma unroll
            for (int r = 0; r < 4; ++r)
                Red[(w - 2) * 2112 + (4 * g + r) * 132 + 16 * dt + l15] = oacc[dt][r];
    __syncthreads();
    if (w < 2)
#pragma unroll
        for (int dt = 0; dt < 8; ++dt)
#pragma unroll
            for (int r = 0; r < 4; ++r)
                oacc[dt][r] += Red[w * 2112 + (4 * g + r) * 132 + 16 * dt + l15];
    __syncthreads();
    if (w == 1)
#pragma unroll
        for (int dt = 0; dt < 8; ++dt)
#pragma unroll
            for (int r = 0; r < 4; ++r)
                Red[(4 * g + r) * 132 + 16 * dt + l15] = oacc[dt][r];
    __syncthreads();
    if (w == 0) {
        float* ob = out + ((size_t)b * 2048 + n0) * 128;
#pragma unroll
        for (int dt = 0; dt < 8; ++dt)
#pragma unroll
            for (int r = 0; r < 4; ++r)
                ob[(size_t)(4 * g + r) * 128 + 16 * dt + l15] =
                    oacc[dt][r] + Red[(4 * g + r) * 132 + 16 * dt + l15];
    }
}

// ---------------------------------------------------------------------------
extern "C" void kernel_launch(void* const* d_in, const int* in_sizes, int n_in,
                              void* d_out, int out_size, void* d_ws, size_t ws_size,
                              hipStream_t stream) {
    const float* x    = (const float*)d_in[0];
    const float* cond = (const float*)d_in[1];
    // d_in[2] = flags (unused by reference)
    const float* mask = (const float*)d_in[3];
    const float* Wq = (const float*)d_in[4];
    const float* bq = (const float*)d_in[5];
    const float* Wk = (const float*)d_in[6];
    const float* bk = (const float*)d_in[7];
    const float* Wv = (const float*)d_in[8];
    const float* bv = (const float*)d_in[9];
    float* out = (float*)d_out;

    char* ws = (char*)d_ws;
    __hip_bfloat16* Qo  = (__hip_bfloat16*)(ws);                       // 4 MB
    __hip_bfloat16* Ko  = (__hip_bfloat16*)(ws + (4  << 20));          // 4 MB
    __hip_bfloat16* Vt  = (__hip_bfloat16*)(ws + (8  << 20));          // 4 MB
    __hip_bfloat16* Wqt = (__hip_bfloat16*)(ws + (12 << 20));          // 32 KB
    __hip_bfloat16* Wkt = (__hip_bfloat16*)(ws + (12 << 20) + 32768);
    __hip_bfloat16* Wvt = (__hip_bfloat16*)(ws + (12 << 20) + 65536);
    float*          bias = (float*)(ws + (12 << 20) + 98304);          // 1.5 KB

    prep_weights<<<64, 256, 0, stream>>>(Wq, bq, Wk, bk, Wv, bv, Wqt, Wkt, Wvt, bias);
    proj_qkv<<<256, 256, 0, stream>>>(x, cond, Wqt, Wkt, Wvt, bias, Qo, Ko, Vt);
    attn_main<<<1024, 256, 0, stream>>>(Qo, Ko, Vt, mask, out);
}